// Round 1
// 1160.454 us; speedup vs baseline: 1.0965x; 1.0965x over previous
//
#include <hip/hip_runtime.h>
#include <hip/hip_fp16.h>
#include <stdint.h>

// MoE top-2: B=2048, D=1024, O=1024, E=8, H=10240, top-2 routing.
#define BTOK 2048
#define DIM 1024
#define ODIM 1024
#define NEXP 8
#define HID 10240
#define CAP 2048
#define KSPL 8

typedef _Float16 half8 __attribute__((ext_vector_type(8)));
typedef __fp16 fp16x2 __attribute__((ext_vector_type(2)));
typedef float floatx4 __attribute__((ext_vector_type(4)));

// ---- workspace layout (bytes) ----
#define WS_HIDDEN_OFF 0
#define WS_COUNTS_OFF 83886080UL
#define WS_TOKENS_OFF 83886144UL
#define WS_PROBS_OFF  83951680UL
#define WS_NEEDED     84017216UL

// ---------------- gate ----------------
__global__ void gate_kernel(const float* __restrict__ x1,
                            const float* __restrict__ gate_w,
                            const float* __restrict__ gate_b,
                            int* counts, int* tokens, float* probs) {
    int b = blockIdx.x;
    int lane = threadIdx.x;
    const float* xr = x1 + (size_t)b * DIM;
    float acc[NEXP];
#pragma unroll
    for (int e = 0; e < NEXP; e++) acc[e] = 0.f;
    for (int i = 0; i < DIM / 64; i++) {
        int d = lane + i * 64;
        float xv = xr[d];
#pragma unroll
        for (int e = 0; e < NEXP; e++) acc[e] += xv * gate_w[e * DIM + d];
    }
#pragma unroll
    for (int e = 0; e < NEXP; e++)
        for (int off = 32; off > 0; off >>= 1) acc[e] += __shfl_xor(acc[e], off);
    if (lane == 0) {
        float l[NEXP], m = -1e30f;
#pragma unroll
        for (int e = 0; e < NEXP; e++) { l[e] = acc[e] + gate_b[e]; m = fmaxf(m, l[e]); }
        float p[NEXP], s = 0.f;
#pragma unroll
        for (int e = 0; e < NEXP; e++) { p[e] = expf(l[e] - m); s += p[e]; }
        float inv = 1.f / s;
        int e0 = 0; float v0 = p[0];
#pragma unroll
        for (int e = 1; e < NEXP; e++) if (p[e] > v0) { v0 = p[e]; e0 = e; }
        int e1 = -1; float v1 = -1.f;
#pragma unroll
        for (int e = 0; e < NEXP; e++) if (e != e0 && p[e] > v1) { v1 = p[e]; e1 = e; }
        int pos0 = atomicAdd(&counts[e0], 1);
        tokens[e0 * CAP + pos0] = b; probs[e0 * CAP + pos0] = v0 * inv;
        int pos1 = atomicAdd(&counts[e1], 1);
        tokens[e1 * CAP + pos1] = b; probs[e1 * CAP + pos1] = v1 * inv;
    }
}

__global__ void offsets_kernel(const int* counts, int* offs) {
    if (threadIdx.x == 0) {
        int r = 0;
        for (int e = 0; e < NEXP; e++) { offs[e] = r; r += counts[e]; }
    }
}

// ---------------- GEMM core geometry ----------------
// 256x256 tile, 1024 threads = 16 waves (4M x 4N), 64x64 per wave, BK=32.
// LDS: fp16 tiles, double-buffered: 2*(16K + 16K) = 64 KB.
// Pipeline: LDS dbuf + 1-tile-deep register prefetch; ONE barrier per K-step.
#define BM 256
#define BN 256
#define BK 32

__device__ __forceinline__ half8 cvt8(float4 a, float4 b) {
    union { fp16x2 h2[4]; half8 h8; } u;
    u.h2[0] = __builtin_amdgcn_cvt_pkrtz(a.x, a.y);
    u.h2[1] = __builtin_amdgcn_cvt_pkrtz(a.z, a.w);
    u.h2[2] = __builtin_amdgcn_cvt_pkrtz(b.x, b.y);
    u.h2[3] = __builtin_amdgcn_cvt_pkrtz(b.z, b.w);
    return u.h8;
}

// GEMM1: hidden = relu(x2[tok] . fc1_w^T + b). fp32 global -> cvt -> fp16 LDS.
__global__ __launch_bounds__(1024, 4) void gemm1_kernel(
    const float* __restrict__ x2, const float* __restrict__ fc1_w,
    const float* __restrict__ fc1_b, const int* __restrict__ counts,
    const int* __restrict__ offs, const int* __restrict__ tokens,
    _Float16* __restrict__ hidden) {
    int d = blockIdx.x;
    // grid = 8 * (40*8); e = d&7 keeps one expert per XCD, mt fastest within
    int e = d & 7;
    int rest = d >> 3;      // [0, 320)
    int nt = rest >> 3;     // [0, 40)
    int mt = rest & 7;      // [0, 8)

    int cnt = counts[e];
    int m0 = mt * BM;
    if (m0 >= cnt) return;
    int n0 = nt * BN;
    int off = offs[e];

    __shared__ __align__(16) _Float16 As[2 * BM * BK];  // 32 KB
    __shared__ __align__(16) _Float16 Bs[2 * BN * BK];  // 32 KB

    int t = threadIdx.x;
    int lane = t & 63, wave = t >> 6;       // wave 0..15
    int waveM = wave >> 2, waveN = wave & 3;
    int fr = lane & 15, q = lane >> 4;

    // staging: thread t owns row srow = t>>2 (0..255), 16B-group sg = t&3 of A AND B
    int srow = t >> 2;
    int sg = t & 3;
    int swz = sg ^ ((srow >> 1) & 3);       // XOR bank swizzle (write side)
    int arow = min(m0 + srow, cnt - 1);
    const float* ag = x2 + (size_t)tokens[e * CAP + arow] * DIM + sg * 8;
    const float* bg = fc1_w + ((size_t)e * HID + n0 + srow) * DIM + sg * 8;
    _Float16* aw = As + srow * BK + swz * 8;
    _Float16* bw = Bs + srow * BK + swz * 8;

    floatx4 acc[4][4];
#pragma unroll
    for (int mi = 0; mi < 4; mi++)
#pragma unroll
        for (int ni = 0; ni < 4; ni++) acc[mi][ni] = (floatx4){0.f, 0.f, 0.f, 0.f};

    float4 pa0, pa1, pb0, pb1;  // in-flight prefetch registers (one K-tile)
    auto LOADT = [&](int kt) {
        const float* a_ = ag + kt * BK;
        const float* b_ = bg + kt * BK;
        pa0 = *(const float4*)a_;
        pa1 = *(const float4*)(a_ + 4);
        pb0 = *(const float4*)b_;
        pb1 = *(const float4*)(b_ + 4);
    };
    auto WRITET = [&](int buf) {
        *(half8*)(aw + buf * (BM * BK)) = cvt8(pa0, pa1);
        *(half8*)(bw + buf * (BN * BK)) = cvt8(pb0, pb1);
    };

    const int KT = DIM / BK;  // 32
    LOADT(0);
    WRITET(0);
    LOADT(1);
    __syncthreads();  // buf0 published; tile-1 loads stay in flight (reg loads)
    int cur = 0;
    for (int kt = 0; kt < KT; kt++) {
        half8 af[4], bf[4];
        const _Float16* Ar = As + cur * (BM * BK);
        const _Float16* Br = Bs + cur * (BN * BK);
#pragma unroll
        for (int mi = 0; mi < 4; mi++) {
            int row = waveM * 64 + mi * 16 + fr;
            af[mi] = *(const half8*)(Ar + row * BK + ((q ^ ((row >> 1) & 3)) * 8));
        }
#pragma unroll
        for (int ni = 0; ni < 4; ni++) {
            int row = waveN * 64 + ni * 16 + fr;
            bf[ni] = *(const half8*)(Br + row * BK + ((q ^ ((row >> 1) & 3)) * 8));
        }
        if (kt + 1 < KT) WRITET(cur ^ 1);   // consume prefetch regs (tile kt+1)
        if (kt + 2 < KT) LOADT(kt + 2);     // issue next loads: full-step latency cover
#pragma unroll
        for (int mi = 0; mi < 4; mi++)
#pragma unroll
            for (int ni = 0; ni < 4; ni++)
                acc[mi][ni] = __builtin_amdgcn_mfma_f32_16x16x32_f16(
                    af[mi], bf[ni], acc[mi][ni], 0, 0, 0);
        __syncthreads();  // publishes buf[cur^1]; reads of buf[cur] complete
        cur ^= 1;
    }
    // epilogue: bias + relu -> fp16 hidden (compact slots)
#pragma unroll
    for (int ni = 0; ni < 4; ni++) {
        int col = n0 + waveN * 64 + ni * 16 + fr;
        float bias = fc1_b[e * HID + col];
#pragma unroll
        for (int mi = 0; mi < 4; mi++) {
#pragma unroll
            for (int r = 0; r < 4; r++) {
                int rl = m0 + waveM * 64 + mi * 16 + q * 4 + r;
                if (rl < cnt) {
                    float v = fmaxf(acc[mi][ni][r] + bias, 0.f);
                    hidden[(size_t)(off + rl) * HID + col] = (_Float16)v;
                }
            }
        }
    }
}

// GEMM2 (split-K x8): A = hidden fp16 (direct), B = fc2_w fp32 -> cvt fp16.
__global__ __launch_bounds__(1024, 4) void gemm2_kernel(
    const _Float16* __restrict__ hidden, const float* __restrict__ fc2_w,
    const float* __restrict__ fc2_b, const int* __restrict__ counts,
    const int* __restrict__ offs, const int* __restrict__ tokens,
    const float* __restrict__ probs, float* __restrict__ out) {
    int d = blockIdx.x;
    // grid = 8 * (8m * 4n * 8k); e = d&7, mt fastest (B-slice L2 reuse in XCD)
    int e = d & 7;
    int rest = d >> 3;          // [0, 256)
    int mt = rest & 7;
    int nt = (rest >> 3) & 3;
    int ks = rest >> 5;         // [0, 8)

    int cnt = counts[e];
    int m0 = mt * BM;
    if (m0 >= cnt) return;
    int n0 = nt * BN;
    int off = offs[e];
    int k0 = ks * (HID / KSPL);  // ks * 1280

    __shared__ __align__(16) _Float16 As[2 * BM * BK];
    __shared__ __align__(16) _Float16 Bs[2 * BN * BK];

    int t = threadIdx.x;
    int lane = t & 63, wave = t >> 6;
    int waveM = wave >> 2, waveN = wave & 3;
    int fr = lane & 15, q = lane >> 4;

    int srow = t >> 2;
    int sg = t & 3;
    int swz = sg ^ ((srow >> 1) & 3);
    int arow = min(m0 + srow, cnt - 1);
    const _Float16* ag = hidden + (size_t)(off + arow) * HID + k0 + sg * 8;
    const float* bg = fc2_w + ((size_t)e * ODIM + n0 + srow) * HID + k0 + sg * 8;
    _Float16* aw = As + srow * BK + swz * 8;
    _Float16* bw = Bs + srow * BK + swz * 8;

    floatx4 acc[4][4];
#pragma unroll
    for (int mi = 0; mi < 4; mi++)
#pragma unroll
        for (int ni = 0; ni < 4; ni++) acc[mi][ni] = (floatx4){0.f, 0.f, 0.f, 0.f};

    half8 pa;              // A prefetch (already fp16)
    float4 pb0, pb1;       // B prefetch (fp32)
    auto LOADT = [&](int kt) {
        pa = *(const half8*)(ag + kt * BK);
        const float* b_ = bg + kt * BK;
        pb0 = *(const float4*)b_;
        pb1 = *(const float4*)(b_ + 4);
    };
    auto WRITET = [&](int buf) {
        *(half8*)(aw + buf * (BM * BK)) = pa;
        *(half8*)(bw + buf * (BN * BK)) = cvt8(pb0, pb1);
    };

    const int KT = (HID / KSPL) / BK;  // 40
    LOADT(0);
    WRITET(0);
    LOADT(1);
    __syncthreads();
    int cur = 0;
    for (int kt = 0; kt < KT; kt++) {
        half8 af[4], bf[4];
        const _Float16* Ar = As + cur * (BM * BK);
        const _Float16* Br = Bs + cur * (BN * BK);
#pragma unroll
        for (int mi = 0; mi < 4; mi++) {
            int row = waveM * 64 + mi * 16 + fr;
            af[mi] = *(const half8*)(Ar + row * BK + ((q ^ ((row >> 1) & 3)) * 8));
        }
#pragma unroll
        for (int ni = 0; ni < 4; ni++) {
            int row = waveN * 64 + ni * 16 + fr;
            bf[ni] = *(const half8*)(Br + row * BK + ((q ^ ((row >> 1) & 3)) * 8));
        }
        if (kt + 1 < KT) WRITET(cur ^ 1);
        if (kt + 2 < KT) LOADT(kt + 2);
#pragma unroll
        for (int mi = 0; mi < 4; mi++)
#pragma unroll
            for (int ni = 0; ni < 4; ni++)
                acc[mi][ni] = __builtin_amdgcn_mfma_f32_16x16x32_f16(
                    af[mi], bf[ni], acc[mi][ni], 0, 0, 0);
        __syncthreads();
        cur ^= 1;
    }
#pragma unroll
    for (int ni = 0; ni < 4; ni++) {
        int col = n0 + waveN * 64 + ni * 16 + fr;
        float bias = (ks == 0) ? fc2_b[e * ODIM + col] : 0.f;
#pragma unroll
        for (int mi = 0; mi < 4; mi++) {
#pragma unroll
            for (int r = 0; r < 4; r++) {
                int rl = m0 + waveM * 64 + mi * 16 + q * 4 + r;
                if (rl < cnt) {
                    float p = probs[e * CAP + rl];
                    int tok = tokens[e * CAP + rl];
                    atomicAdd(&out[(size_t)tok * ODIM + col],
                              p * (acc[mi][ni][r] + bias));
                }
            }
        }
    }
}

extern "C" void kernel_launch(void* const* d_in, const int* in_sizes, int n_in,
                              void* d_out, int out_size, void* d_ws, size_t ws_size,
                              hipStream_t stream) {
    if (ws_size < WS_NEEDED) return;
    const float* x1 = (const float*)d_in[0];
    const float* x2 = (const float*)d_in[1];
    const float* gate_w = (const float*)d_in[2];
    const float* gate_b = (const float*)d_in[3];
    const float* fc1_w = (const float*)d_in[4];
    const float* fc1_b = (const float*)d_in[5];
    const float* fc2_w = (const float*)d_in[6];
    const float* fc2_b = (const float*)d_in[7];
    float* out = (float*)d_out;
    char* ws = (char*)d_ws;
    _Float16* hidden = (_Float16*)(ws + WS_HIDDEN_OFF);
    int* counts = (int*)(ws + WS_COUNTS_OFF);
    int* offs = counts + NEXP;
    int* tokens = (int*)(ws + WS_TOKENS_OFF);
    float* probs = (float*)(ws + WS_PROBS_OFF);

    (void)hipMemsetAsync(counts, 0, 2 * NEXP * sizeof(int), stream);
    (void)hipMemsetAsync(d_out, 0, (size_t)out_size * sizeof(float), stream);
    gate_kernel<<<BTOK, 64, 0, stream>>>(x1, gate_w, gate_b, counts, tokens, probs);
    offsets_kernel<<<1, 64, 0, stream>>>(counts, offs);
    gemm1_kernel<<<(CAP / BM) * (HID / BN) * NEXP, 1024, 0, stream>>>(
        x2, fc1_w, fc1_b, counts, offs, tokens, hidden);
    gemm2_kernel<<<(CAP / BM) * (ODIM / BN) * NEXP * KSPL, 1024, 0, stream>>>(
        hidden, fc2_w, fc2_b, counts, offs, tokens, probs, out);
}